// Round 11
// baseline (700.880 us; speedup 1.0000x reference)
//
#include <hip/hip_runtime.h>
#include <stdint.h>

#define MDIM 8192
#define NDIM 16384
#define KDIM 4096
#define NT   64          // K-steps of 64

typedef __attribute__((ext_vector_type(4))) int i32x4;

__device__ __forceinline__ void gload_lds16(const void* g, void* l) {
    __builtin_amdgcn_global_load_lds(
        (const __attribute__((address_space(1))) void*)g,
        (__attribute__((address_space(3))) void*)l,
        16, 0, 0);
}

__device__ __forceinline__ i32x4 MFMA8(i32x4 a, i32x4 b, i32x4 c) {
    return __builtin_amdgcn_mfma_i32_16x16x64_i8(a, b, c, 0, 0, 0);
}

// ---------------- quantization kernels (unchanged, round-6 verified) ----------------

__global__ __launch_bounds__(256)
void quant_x_kernel(const float* __restrict__ x, int8_t* __restrict__ xq,
                    float* __restrict__ sx) {
    const int row = (int)blockIdx.x;
    const float* xr = x + (long)row * KDIM;
    const int t = threadIdx.x;
    float v[16];
#pragma unroll
    for (int i = 0; i < 4; ++i)
        *(float4*)&v[i * 4] = ((const float4*)xr)[t + 256 * i];
    float m = 0.f;
#pragma unroll
    for (int i = 0; i < 16; ++i) m = fmaxf(m, fabsf(v[i]));
#pragma unroll
    for (int off = 32; off >= 1; off >>= 1) m = fmaxf(m, __shfl_xor(m, off));
    __shared__ float red[4];
    if ((t & 63) == 0) red[t >> 6] = m;
    __syncthreads();
    m = fmaxf(fmaxf(red[0], red[1]), fmaxf(red[2], red[3]));
    m = fmaxf(m, 1e-20f);
    const float inv = 127.0f / m;
    if (t == 0) sx[row] = m * (1.0f / 127.0f);
    int* qo = (int*)(xq + (long)row * KDIM);
#pragma unroll
    for (int i = 0; i < 4; ++i) {
        union { int8_t c[4]; int w; } o;
#pragma unroll
        for (int j = 0; j < 4; ++j)
            o.c[j] = (int8_t)__float2int_rn(v[i * 4 + j] * inv);
        qo[t + 256 * i] = o.w;
    }
}

__global__ __launch_bounds__(256)
void quant_w_kernel(const int* __restrict__ q, const int* __restrict__ zp,
                    int8_t* __restrict__ wq) {
    const long i = (long)blockIdx.x * 256 + threadIdx.x;
    const long e = i * 16;
    const int o = (int)(e >> 12);          // KDIM = 4096
    const int z = zp[o];
    union { int8_t c[16]; int4 v; } r;
#pragma unroll
    for (int b = 0; b < 4; ++b) {
        int4 a = ((const int4*)(q + e))[b];
        r.c[b * 4 + 0] = (int8_t)(a.x - z);
        r.c[b * 4 + 1] = (int8_t)(a.y - z);
        r.c[b * 4 + 2] = (int8_t)(a.z - z);
        r.c[b * 4 + 3] = (int8_t)(a.w - z);
    }
    *(int4*)(wq + e) = r.v;
}

// -- 256x256 8-wave int8 GEMM: 4-buf stage-3-ahead, reads pipelined 1 quadrant early --
// C[m,n] = scale[n] * sx[m] * sum_k xq[m,k] * wq[n,k]   (i32 accum, exact)
// LDS: 4 bufs x 32 KB = 128 KB (dynamic). Buf: Ah0[0,8K) Ah1[8K,16K) Bh0[16K,24K)
// Bh1[24K,32K); each half-plane = ONE gload_lds line. XOR chunk swizzle
// sc = c ^ ((r>>1)&3) via pre-swizzled global source (rounds 6-10: conflicts 0).
//
// Pipeline: every ds_read issues ONE MFMA-quadrant before its consumer, so the
// LDS pipe retires frags while the matrix pipe runs (the overlap rounds 6-10
// lacked). Per tile t (b0=B[t]..b3=B[t+3], 4-cycle rotate):
//   ph0: issue aHi(t);            lgkm(4) [primed aLo/bLo done]; MFQ(0,0)
//   ph1: issue bHi(t);            lgkm(2) [aHi done];            MFQ(4,0)
//   ph2: prime aLo/bLo(t+1)<-b1;  lgkm(6) [bHi done];            MFQ(0,2)
//   ph3: STG x4 (tile t+3 -> b3); vmcnt(4); s_barrier;           MFQ(4,2)
// RAW ledger: vmcnt(4)@ph3(t) leaves only stages(t+3) outstanding => tile t+2
// landed => primed reads @ph2(t+1) of B[t+2] safe (barrier makes it cross-wave).
// Prologue: stage tiles 0,1,2 (12 loads); vmcnt(4) => tiles 0,1 landed; prime t0.
// WAR ledger: STG@ph3(t) targets B[t+3]=B[t-1]-alias; all B[t-1] reads (last:
// bHi(t-1)) completed at each wave's lgkm(6)@ph2(t-1), before the ph3(t-1)
// barrier, >=1 full tile before this STG. Tail: t=63 skips prime (lgkm(0));
// dummy STG clamped to tile 63 land in never-again-read buffers.
// Frag regs ping-pong (static names, rule #20): aLoA/B, bLoA/B + aHi, bHi.
//
// Block mapping (round-3 verified): round = 256 blocks covers ALL 32 A-panels
// x 8 B-panels; inputs (100 MB int8) L3-resident.

__global__ __launch_bounds__(512, 2)
void gemm_i8_kernel(const int8_t* __restrict__ A, const int8_t* __restrict__ Wt,
                    const float* __restrict__ scale, const float* __restrict__ sx,
                    float* __restrict__ C) {
    extern __shared__ int8_t lds[];   // 131072

    const int wg = (int)blockIdx.x;
    const int rr = wg >> 8;                   // round 0..7
    const int ii = wg & 255;
    const int bm = ii & 31;                   // all 32 A-panels each round
    const int bn = rr * 8 + (ii >> 5);        // 8 fresh B-panels per round

    const int tid  = threadIdx.x;
    const int lane = tid & 63;
    const int wid  = tid >> 6;
    const int wm   = wid >> 2;        // 0..1 (128 rows)
    const int wn   = wid & 3;         // 0..3 (64 cols)
    const int l15  = lane & 15;
    const int c16  = lane >> 4;       // 0..3 = logical k-chunk (16 i8)

    const int axor = (l15 >> 1) & 3;
    const int fro  = l15 * 64 + ((c16 ^ axor) << 4);

    const int soff = (tid >> 2) * KDIM + ((((tid & 3) ^ ((tid >> 3) & 3))) << 4);
    const int dl   = tid * 16;

    const int8_t* Ab  = A  + (long)bm * 256 * KDIM;
    const int8_t* Wb  = Wt + (long)bn * 256 * KDIM;
    const int8_t* Ab2 = Ab + (long)128 * KDIM;
    const int8_t* Wb2 = Wb + (long)128 * KDIM;

#define STG(DSTB, SRC, TT) gload_lds16((SRC) + soff + (TT) * 64, &lds[(DSTB) + dl])

#define RDA4(DST, BB, IB)                                                           \
    _Pragma("unroll")                                                               \
    for (int i_ = 0; i_ < 4; ++i_)                                                  \
        DST[i_] = *(const i32x4*)&lds[(BB) + (wm * 128 + ((IB) + i_) * 16) * 64 + fro];

#define RDB2(DST, BB, JB)                                                           \
    _Pragma("unroll")                                                               \
    for (int j_ = 0; j_ < 2; ++j_)                                                  \
        DST[j_] = *(const i32x4*)&lds[(BB) + 16384 + (wn * 64 + ((JB) + j_) * 16) * 64 + fro];

#define MFQ(IB, JB, AS, BS)                                                         \
    do {                                                                            \
        __builtin_amdgcn_sched_barrier(0);                                          \
        __builtin_amdgcn_s_setprio(1);                                              \
        _Pragma("unroll")                                                           \
        for (int i_ = 0; i_ < 4; ++i_)                                              \
            _Pragma("unroll")                                                       \
            for (int j_ = 0; j_ < 2; ++j_)                                          \
                acc[(IB) + i_][(JB) + j_] =                                         \
                    MFMA8(AS[i_], BS[j_], acc[(IB) + i_][(JB) + j_]);               \
        __builtin_amdgcn_s_setprio(0);                                              \
        __builtin_amdgcn_sched_barrier(0);                                          \
    } while (0)

// One K-tile; reads pipelined one quadrant ahead of use.
#define TILE(T, ACUR, BCUR, ANXT, BNXT)                                             \
    do {                                                                            \
        /* ph0: issue aHi(T); primed ACUR/BCUR (issued last tile) now waited */     \
        RDA4(aHi, b0, 4);                                                           \
        asm volatile("s_waitcnt lgkmcnt(4)" ::: "memory");                          \
        MFQ(0, 0, ACUR, BCUR);                                                      \
        /* ph1: issue bHi(T) */                                                     \
        RDB2(bHi, b0, 2);                                                           \
        asm volatile("s_waitcnt lgkmcnt(2)" ::: "memory");                          \
        MFQ(4, 0, aHi, BCUR);                                                       \
        /* ph2: prime next tile's aLo/bLo from b1 */                                \
        if ((T) < NT - 1) {                                                         \
            RDA4(ANXT, b1, 0);                                                      \
            RDB2(BNXT, b1, 0);                                                      \
            asm volatile("s_waitcnt lgkmcnt(6)" ::: "memory");                      \
        } else {                                                                    \
            asm volatile("s_waitcnt lgkmcnt(0)" ::: "memory");                      \
        }                                                                           \
        MFQ(0, 2, ACUR, bHi);                                                       \
        /* ph3: stage tile T+3 into b3; counted vmcnt; single barrier */            \
        {                                                                           \
            const int tt = ((T) + 3 < NT) ? ((T) + 3) : (NT - 1);                   \
            STG(b3 + 0, Ab, tt);  STG(b3 + 16384, Wb, tt);                          \
            STG(b3 + 8192, Ab2, tt); STG(b3 + 24576, Wb2, tt);                      \
        }                                                                           \
        asm volatile("s_waitcnt vmcnt(4)" ::: "memory");                            \
        __builtin_amdgcn_s_barrier();                                               \
        MFQ(4, 2, aHi, bHi);                                                        \
        { const int tb = b0; b0 = b1; b1 = b2; b2 = b3; b3 = tb; }                  \
    } while (0)

    i32x4 acc[8][4];
#pragma unroll
    for (int i = 0; i < 8; ++i)
#pragma unroll
        for (int j = 0; j < 4; ++j) acc[i][j] = (i32x4){0, 0, 0, 0};

    i32x4 aLoA[4], aLoB[4], aHi[4];
    i32x4 bLoA[2], bLoB[2], bHi[2];

    int b0 = 0, b1 = 32768, b2 = 65536, b3 = 98304;

    // prologue: stage tiles 0,1,2 (12 loads, tile-major); tiles 0,1 landed; prime t0
    STG(b0 + 0, Ab, 0); STG(b0 + 16384, Wb, 0); STG(b0 + 8192, Ab2, 0); STG(b0 + 24576, Wb2, 0);
    STG(b1 + 0, Ab, 1); STG(b1 + 16384, Wb, 1); STG(b1 + 8192, Ab2, 1); STG(b1 + 24576, Wb2, 1);
    STG(b2 + 0, Ab, 2); STG(b2 + 16384, Wb, 2); STG(b2 + 8192, Ab2, 2); STG(b2 + 24576, Wb2, 2);
    asm volatile("s_waitcnt vmcnt(4)" ::: "memory");   // tiles 0,1 landed
    __builtin_amdgcn_s_barrier();
    RDA4(aLoA, b0, 0);
    RDB2(bLoA, b0, 0);

    for (int t = 0; t < NT; t += 2) {
        TILE(t,     aLoA, bLoA, aLoB, bLoB);
        TILE(t + 1, aLoB, bLoB, aLoA, bLoA);
    }
#undef TILE
#undef STG
#undef RDA4
#undef RDB2
#undef MFQ

    // epilogue: D mapping col=lane&15, row=(lane>>4)*4+reg (m89-verified)
    const long rowA0 = (long)bm * 256 + wm * 128;
    const int  colB0 = bn * 256 + wn * 64;
    float scj[4];
#pragma unroll
    for (int j = 0; j < 4; ++j) scj[j] = scale[colB0 + j * 16 + l15];
#pragma unroll
    for (int i = 0; i < 8; ++i) {
        const long rbase = rowA0 + i * 16 + c16 * 4;
        const float4 s4 = *(const float4*)(sx + rbase);
#pragma unroll
        for (int j = 0; j < 4; ++j) {
            float* cp = C + rbase * NDIM + colB0 + j * 16 + l15;
            cp[0 * (long)NDIM] = (float)acc[i][j][0] * scj[j] * s4.x;
            cp[1 * (long)NDIM] = (float)acc[i][j][1] * scj[j] * s4.y;
            cp[2 * (long)NDIM] = (float)acc[i][j][2] * scj[j] * s4.z;
            cp[3 * (long)NDIM] = (float)acc[i][j][3] * scj[j] * s4.w;
        }
    }
}

// ---------------- safety fallback (no workspace needed, fp32, slow) ----------------

__global__ __launch_bounds__(256)
void fallback_kernel(const float* __restrict__ x, const int* __restrict__ q,
                     const float* __restrict__ scale, const int* __restrict__ zp,
                     float* __restrict__ out) {
    __shared__ float sA[64][17];
    __shared__ float sB[64][17];
    const int bn = (int)blockIdx.x % (NDIM / 64);
    const int bm = (int)blockIdx.x / (NDIM / 64);
    const int t  = threadIdx.x;
    const int tx = t & 15, ty = t >> 4;
    const long rowA = (long)bm * 64, rowB = (long)bn * 64;
    float acc[4][4] = {};
    for (int k0 = 0; k0 < KDIM; k0 += 16) {
#pragma unroll
        for (int i = 0; i < 4; ++i) {
            const int e = t + i * 256;
            const int r = e >> 4, c = e & 15;
            sA[r][c] = x[(rowA + r) * KDIM + k0 + c];
            const int o = (int)rowB + r;
            sB[r][c] = (float)(q[(long)o * KDIM + k0 + c] - zp[o]) * scale[o];
        }
        __syncthreads();
#pragma unroll
        for (int kk = 0; kk < 16; ++kk) {
            float a[4], b[4];
#pragma unroll
            for (int i = 0; i < 4; ++i) a[i] = sA[ty * 4 + i][kk];
#pragma unroll
            for (int j = 0; j < 4; ++j) b[j] = sB[tx * 4 + j][kk];
#pragma unroll
            for (int i = 0; i < 4; ++i)
#pragma unroll
                for (int j = 0; j < 4; ++j) acc[i][j] += a[i] * b[j];
        }
        __syncthreads();
    }
#pragma unroll
    for (int i = 0; i < 4; ++i) {
        const long r = rowA + ty * 4 + i;
#pragma unroll
        for (int j = 0; j < 4; ++j)
            out[r * NDIM + rowB + tx * 4 + j] = acc[i][j];
    }
}

// ---------------- launch ----------------

extern "C" void kernel_launch(void* const* d_in, const int* in_sizes, int n_in,
                              void* d_out, int out_size, void* d_ws, size_t ws_size,
                              hipStream_t stream) {
    const float* x     = (const float*)d_in[0];
    const int*   qw    = (const int*)d_in[1];
    const float* scale = (const float*)d_in[2];
    const int*   zp    = (const int*)d_in[3];
    float*       out   = (float*)d_out;

    const size_t needA  = (size_t)MDIM * KDIM;          // 33.5 MB int8
    const size_t needW  = (size_t)NDIM * KDIM;          // 67.1 MB int8
    const size_t needSx = (size_t)MDIM * sizeof(float); // 32 KB

    if (ws_size >= needA + needW + needSx) {
        int8_t* xq = (int8_t*)d_ws;
        int8_t* wq = xq + needA;
        float*  sx = (float*)((char*)d_ws + needA + needW);
        quant_x_kernel<<<MDIM, 256, 0, stream>>>(x, xq, sx);
        quant_w_kernel<<<(NDIM * (KDIM / 16)) / 256, 256, 0, stream>>>(qw, zp, wq);
        (void)hipFuncSetAttribute((const void*)gemm_i8_kernel,
                                  hipFuncAttributeMaxDynamicSharedMemorySize, 131072);
        gemm_i8_kernel<<<(MDIM / 256) * (NDIM / 256), 512, 131072, stream>>>(xq, wq, scale, sx, out);
    } else {
        fallback_kernel<<<(MDIM / 64) * (NDIM / 64), 256, 0, stream>>>(x, qw, scale, zp, out);
    }
}